// Round 2
// 525.691 us; speedup vs baseline: 1.2727x; 1.2727x over previous
//
#include <hip/hip_runtime.h>
#include <math.h>

// PhaseNN on MI355X.  ROUND 13 = ROUND 12 resubmitted (container infra failure,
// no kernel signal).  Wave-width state split + trig cache.
// R11 baseline (627 us): per-active-CU VALUBusy ~50%; Phase A + RK4 run
// half-masked (act = b16<8) and RK4 recomputes sin/cos(pwv) that Phase A
// already produced (pwv is constant within an eval).
// Changes vs R11, zero extra MFMA work:
//  (a) B-operand duplication: encoder B cols 8..15 <- x rows 0..7, softmax W
//      rows 8..15 <- rows 0..7.  Pad MFMA columns now deliver each row's
//      encoder/GEMM2 outputs to lanes b16>=8 for free (no shuffles).
//  (b) Each lane owns 8 phases (j = jloc + 2*hi, row = b16&7) instead of 16
//      on act lanes: Phase A trig 32->16 trans-inst/wave, RK4 halved and
//      unmasked; per-lane state 48->24 f32.
//  (c) RK4 reuses Phase A's cached sin/cos (csv/snv[8]) -> RK4 trig 32->0.
//  (d) GEMM1 split into independent cos/sin accumulators (chain 32->16).
//  (e) amdgpu_waves_per_eu(4,4) to unpin the 64-VGPR allocator budget
//      (R10: allocator pinned 64 and spilled; design now needs ~100 <= 128).
// Structure otherwise identical to R9/R11: 32 blocks x 1024 thr, 8 rows/block,
// fp8 e4m3 tables/feats/w (x64 prescale), 3 barriers/eval, no cross-block traffic.
// ws: 512 KiB tables (T1 256K | T2 256K), rewritten by every block (identical bytes).

typedef __attribute__((ext_vector_type(4))) float f32x4;
typedef __attribute__((ext_vector_type(2))) float f32x2;
typedef __attribute__((ext_vector_type(8))) short bf16x8;
typedef __attribute__((ext_vector_type(4))) unsigned short u16x4;
typedef __attribute__((ext_vector_type(2))) long i64x2;

struct TCons { float s[64]; float c[64]; };

__device__ __forceinline__ unsigned short f2bf(float f) {
  unsigned u = __builtin_bit_cast(unsigned, f);
  return (unsigned short)((u + 0x7FFFu + ((u >> 16) & 1u)) >> 16);
}
// pack 8 floats -> 8 fp8 e4m3 bytes (HW cvt: byte i <-> value i, LSB first)
__device__ __forceinline__ long pk8fp8(const float* v) {
  unsigned lo = __builtin_amdgcn_cvt_pk_fp8_f32(v[0], v[1], 0, false);
  lo = __builtin_amdgcn_cvt_pk_fp8_f32(v[2], v[3], lo, true);
  unsigned hi = __builtin_amdgcn_cvt_pk_fp8_f32(v[4], v[5], 0, false);
  hi = __builtin_amdgcn_cvt_pk_fp8_f32(v[6], v[7], hi, true);
  return (long)lo | ((long)hi << 32);
}

#define A1_OFF    0        // feats fp8: 16 rows x 256 units x 8 B = 32768 (unit^row)
#define MBUF_OFF  32768    // m partials: 2 kh x 8 rows x 132 f32 = 8448
#define W_OFF     41216    // w fp8 (x64): 16 rows x 16 units x 8 B = 2048 (unit^row)
#define XST_OFF   43264    // 8 rows x 104 chunks x 16 B bf16 (encoder prologue only)
#define RED_OFF   32768    // epilogue overlay: 16 waves x 64 lanes x 16 B
#define ZP_OFF    56576    // 16 B zero page (bf16 epilogue pad cols)
#define LDS_BYTES 56592

__global__
__attribute__((amdgpu_flat_work_group_size(1024, 1024), amdgpu_waves_per_eu(4, 4)))
void phasenn_kernel(
    const float* __restrict__ x, const float* __restrict__ W_enc,
    const float* __restrict__ b_enc, const float* __restrict__ xi,
    const float* __restrict__ W_out, const float* __restrict__ b_out,
    float* __restrict__ dout, char* __restrict__ wsb, TCons tc)
{
  __shared__ __align__(16) char smem[LDS_BYTES];

  const int tid  = threadIdx.x;
  const int bk   = blockIdx.x;        // rows bk*8 .. bk*8+7
  const int w    = tid >> 6;          // 16 waves
  const int lane = tid & 63;
  const int q    = lane >> 4;
  const int b16  = lane & 15;         // MFMA col slot (batch row duplicated hi/lo)
  const int hi   = b16 >> 3;          // lane owns j = jloc + 2*hi
  const int row8 = b16 & 7;           // batch row within block
  const bool act = (b16 < 8);

  char* T1g = wsb;                    // 256 KiB: (pt 8, ktc 32) x 64 lanes x [cos8|sin8]
  char* T2g = wsb + (256 << 10);      // 256 KiB: (ct 64, pt2 4) x 64 lanes x [cos8|sin8]

  // ---- LDS init (before first barrier): zero pads so hot loops are branchless
  *(f32x4*)(smem + A1_OFF + 16384 + tid*16) = (f32x4){0,0,0,0};  // A1 rows 8..15
  if (tid < 256) *(unsigned*)(smem + W_OFF + 1024 + tid*4) = 0;  // W rows 8..15
  if (tid < 4)   *(unsigned*)(smem + ZP_OFF + tid*4) = 0;

  // ---- xstage: x rows -> bf16 B-frag chunks (chunk ^ row), d>=784 zero (encoder)
  {
    const int row = tid >> 7, dg = tid & 127;
    if (dg < 100) {
      bf16x8 fr = {0,0,0,0,0,0,0,0};
      if (dg < 98) {
        f32x4 v0 = *(const f32x4*)(x + (bk*8 + row)*784 + dg*8);
        f32x4 v1 = *(const f32x4*)(x + (bk*8 + row)*784 + dg*8 + 4);
        #pragma unroll
        for (int i = 0; i < 8; ++i) fr[i] = (short)f2bf(i < 4 ? v0[i] : v1[i-4]);
      }
      *(bf16x8*)(smem + XST_OFF + row*1664 + (((dg ^ row) & 127) << 4)) = fr;
    }
  }

  // ---- table gen: fp8 paired frags (identical bytes from every block; plain stores)
  if (w < 8) {  // T1: wave = ptile. lane holds p=w*16+b16, n = f*32+q*8+i; [cos|sin]
    const int p = w*16 + b16;
    for (int f = 0; f < 32; ++f) {
      const int n0 = f*32 + q*8;
      f32x4 v0 = *(const f32x4*)(xi + p*1024 + n0);
      f32x4 v1 = *(const f32x4*)(xi + p*1024 + n0 + 4);
      float cv[8], sv[8];
      #pragma unroll
      for (int i = 0; i < 8; ++i) {
        float xv = (i < 4) ? v0[i] : v1[i-4];
        sv[i] = __sinf(xv); cv[i] = __cosf(xv);
      }
      i64x2 pr; pr[0] = pk8fp8(cv); pr[1] = pk8fp8(sv);
      *(i64x2*)(T1g + (size_t)((w*32 + f)*64 + lane)*16) = pr;
    }
  } else {      // T2: lane holds n = ct*16+b16, p = pt2*32+q*8+i; [cos|sin]
    const int w2 = w - 8;
    for (int f = 0; f < 32; ++f) {
      const int ct = w2*8 + (f >> 2), pt2 = f & 3;
      const int n = ct*16 + b16;
      float cv[8], sv[8];
      #pragma unroll
      for (int i = 0; i < 8; ++i) {
        float xv = xi[(pt2*32 + q*8 + i)*1024 + n];
        sv[i] = __sinf(xv); cv[i] = __cosf(xv);
      }
      i64x2 pr; pr[0] = pk8fp8(cv); pr[1] = pk8fp8(sv);
      *(i64x2*)(T2g + (size_t)((ct*4 + pt2)*64 + lane)*16) = pr;
    }
  }
  __syncthreads();

  // ---- encoder (bf16 MFMA): B cols 8..15 duplicate rows 0..7 so hi lanes get
  // their j=2,3 outputs directly.  Lane owns 8 phases: n=(w*4+jloc+2*hi)*16+q*4+r.
  float p0[8], ka[8], pwv[8];
  {
    f32x4 pac[4] = {{0,0,0,0},{0,0,0,0},{0,0,0,0},{0,0,0,0}};
    for (int kt = 0; kt < 25; ++kt) {
      const char* baddr =
          smem + XST_OFF + row8*1664 + ((((kt*4 + q) ^ row8) & 127) << 4);
      bf16x8 bfr = *(const bf16x8*)baddr;
      const int d = kt*32 + q*8;
      #pragma unroll
      for (int j = 0; j < 4; ++j) {
        bf16x8 afr = {0,0,0,0,0,0,0,0};
        if (d < 784) {
          const int n = (w*4 + j)*16 + b16;
          f32x4 v0 = *(const f32x4*)(W_enc + n*784 + d);
          f32x4 v1 = *(const f32x4*)(W_enc + n*784 + d + 4);
          #pragma unroll
          for (int i = 0; i < 8; ++i) afr[i] = (short)f2bf(i < 4 ? v0[i] : v1[i-4]);
        }
        pac[j] = __builtin_amdgcn_mfma_f32_16x16x32_bf16(afr, bfr, pac[j], 0, 0, 0);
      }
    }
    f32x4 pcA = hi ? pac[2] : pac[0];   // static-index select (rule #20 safe)
    f32x4 pcB = hi ? pac[3] : pac[1];
    #pragma unroll
    for (int r = 0; r < 4; ++r) {
      const int n0 = (w*4 + 2*hi)*16 + q*4 + r;
      float ph0 = 6.283185307179586f / (1.0f + __expf(-(pcA[r] + b_enc[n0])));
      p0[r] = ph0; pwv[r] = ph0; ka[r] = 0.0f;
      const int n1 = (w*4 + 1 + 2*hi)*16 + q*4 + r;
      float ph1 = 6.283185307179586f / (1.0f + __expf(-(pcB[r] + b_enc[n1])));
      p0[4+r] = ph1; pwv[4+r] = ph1; ka[4+r] = 0.0f;
    }
  }

  const float dtf = 0.03125f, half = 0.015625f;
  const float sixth = (float)(0.03125/6.0);

  for (int e = 0; e < 64; ++e) {
    float csv[8], snv[8];
    // ---- Phase A: all 64 lanes, 8 phases each; cache sin/cos for RK4 reuse
    #pragma unroll
    for (int jloc = 0; jloc < 2; ++jloc) {
      #pragma unroll
      for (int r = 0; r < 4; ++r) {
        const int ix = jloc*4 + r;
        snv[ix] = __sinf(pwv[ix]);
        csv[ix] = __cosf(pwv[ix]);
      }
      unsigned cp = __builtin_amdgcn_cvt_pk_fp8_f32(csv[jloc*4+0], csv[jloc*4+1], 0, false);
      cp = __builtin_amdgcn_cvt_pk_fp8_f32(csv[jloc*4+2], csv[jloc*4+3], cp, true);
      unsigned sp = __builtin_amdgcn_cvt_pk_fp8_f32(snv[jloc*4+0], snv[jloc*4+1], 0, false);
      sp = __builtin_amdgcn_cvt_pk_fp8_f32(snv[jloc*4+2], snv[jloc*4+3], sp, true);
      const int u = (w*4 + jloc + 2*hi)*2 + (q >> 1);
      char* base = smem + A1_OFF + row8*2048 + ((q & 1) << 2);
      *(unsigned*)(base + ((u ^ row8) << 3))        = cp;   // cos: units 0..127
      *(unsigned*)(base + 1024 + ((u ^ row8) << 3)) = sp;   // sin: units 128..255
    }
    __syncthreads();

    // ---- GEMM1 fp8: m[p][row]; wave = (pt=w&7, kh=w>>3); independent cos/sin accs
    {
      const int pt = w & 7, kh = w >> 3;
      f32x4 accC = {0.f, 0.f, 0.f, 0.f}, accS = {0.f, 0.f, 0.f, 0.f};
      const char* t1b = T1g + (size_t)((pt*32 + kh*16)*64 + lane)*16;
      const char* a1b = smem + A1_OFF + b16*2048;
      #pragma unroll 8
      for (int i2 = 0; i2 < 16; ++i2) {
        const int ktc = kh*16 + i2;
        i64x2 af = *(const i64x2*)(t1b + (size_t)i2*1024);
        long bc = *(const long*)(a1b + (((ktc*4 + q) ^ b16) << 3));
        long bs = *(const long*)(a1b + 1024 + (((ktc*4 + q) ^ b16) << 3));
        accC = __builtin_amdgcn_mfma_f32_16x16x32_fp8_fp8(af[0], bc, accC, 0, 0, 0);
        accS = __builtin_amdgcn_mfma_f32_16x16x32_fp8_fp8(af[1], bs, accS, 0, 0, 0);
      }
      if (act) {
        f32x4 acc = accC + accS;
        *(f32x4*)(smem + MBUF_OFF + kh*4224 + b16*528 + ((pt*16 + q*4) << 2)) = acc;
      }
    }
    __syncthreads();

    // ---- softmax (waves 0..7, wave = row): w fp8 prescaled x64; DUP store to
    // rows 8..15 so GEMM2's pad cols compute each row's sums for the hi lanes.
    if (w < 8) {
      const char* mb = smem + MBUF_OFF + w*528 + lane*8;
      f32x2 u0 = *(const f32x2*)(mb);
      f32x2 u1 = *(const f32x2*)(mb + 4224);
      float e0 = __expf((u0[0] + u1[0]) * 0.001953125f);  // BETA/N = 2/1024
      float e1 = __expf((u0[1] + u1[1]) * 0.001953125f);
      float s = e0 + e1;
      #pragma unroll
      for (int off = 1; off < 64; off <<= 1) s += __shfl_xor(s, off, 64);
      const float inv64 = 64.0f / s;
      unsigned pk = __builtin_amdgcn_cvt_pk_fp8_f32(e0*inv64, e1*inv64, 0, false);
      const int pp = lane*2, u = pp >> 3;
      *(unsigned short*)(smem + W_OFF + w*128 + ((u ^ w) << 3) + (pp & 7)) =
          (unsigned short)pk;
      *(unsigned short*)(smem + W_OFF + (w+8)*128 + ((u ^ (w+8)) << 3) + (pp & 7)) =
          (unsigned short)pk;
    }
    __syncthreads();

    // ---- GEMM2 fp8 + RK4: keep both ps halves, per-lane select (ps = hi), then
    // unmasked 8-phase RK4 with cached trig (no sin/cos here at all).
    {
      const float swt = tc.s[e], cwt = tc.c[e];
      const int st = e & 3;
      long wfr[4];
      #pragma unroll
      for (int pt2 = 0; pt2 < 4; ++pt2)
        wfr[pt2] = *(const long*)(smem + W_OFF + b16*128 + (((pt2*4 + q) ^ b16) << 3));
      f32x4 aCk[2][2] = {{{0,0,0,0},{0,0,0,0}},{{0,0,0,0},{0,0,0,0}}};
      f32x4 aSk[2][2] = {{{0,0,0,0},{0,0,0,0}},{{0,0,0,0},{0,0,0,0}}};
      #pragma unroll
      for (int ps = 0; ps < 2; ++ps)
        #pragma unroll
        for (int jj = 0; jj < 2; ++jj) {
          const int ct = w*4 + ps*2 + jj;
          #pragma unroll
          for (int pt2 = 0; pt2 < 4; ++pt2) {
            i64x2 tf = *(const i64x2*)(T2g + (size_t)((ct*4 + pt2)*64 + lane)*16);
            aCk[ps][jj] = __builtin_amdgcn_mfma_f32_16x16x32_fp8_fp8(tf[0], wfr[pt2], aCk[ps][jj], 0,0,0);
            aSk[ps][jj] = __builtin_amdgcn_mfma_f32_16x16x32_fp8_fp8(tf[1], wfr[pt2], aSk[ps][jj], 0,0,0);
          }
        }
      #pragma unroll
      for (int jloc = 0; jloc < 2; ++jloc) {
        #pragma unroll
        for (int r = 0; r < 4; ++r) {
          const int ix = jloc*4 + r;
          float vC = hi ? aCk[1][jloc][r] : aCk[0][jloc][r];
          float vS = hi ? aSk[1][jloc][r] : aSk[0][jloc][r];
          float s_ = snv[ix];
          float c_ = csv[ix];
          float kv = (s_*vC - c_*vS) * 0.015625f   // /64 rescale
                   + 0.08f*(swt*c_ - cwt*s_);      // A*sin(wt - phi)
          if (st == 0)      { ka[ix]  = kv;           pwv[ix] = p0[ix] + kv*half; }
          else if (st == 1) { ka[ix] += 2.0f*kv;      pwv[ix] = p0[ix] + kv*half; }
          else if (st == 2) { ka[ix] += 2.0f*kv;      pwv[ix] = p0[ix] + kv*dtf;  }
          else { ka[ix] += kv; p0[ix] += ka[ix]*sixth; pwv[ix] = p0[ix]; }
        }
      }
    }
  }

  // ---- epilogue (bf16 MFMA): out = [cos phiT, sin phiT] @ W_out^T + b_out
  __syncthreads();
  {  // pack feats bf16 into A1 region (rows 0..7, 4-KB stride); all lanes, 8 each
    #pragma unroll
    for (int jloc = 0; jloc < 2; ++jloc) {
      u16x4 cp, sp;
      #pragma unroll
      for (int r = 0; r < 4; ++r) {
        float ph = p0[jloc*4 + r];
        cp[r] = f2bf(__cosf(ph)); sp[r] = f2bf(__sinf(ph));
      }
      const int cj = (w*4 + jloc + 2*hi)*2 + (q >> 1);
      char* base = smem + A1_OFF + row8*4096 + ((q & 1) << 3);
      *(u16x4*)(base + ((cj ^ row8) << 4))        = cp;
      *(u16x4*)(base + ((cj ^ row8) << 4) + 2048) = sp;
    }
  }
  __syncthreads();
  {  // D[cl][row] partial over this wave's 4 ktiles; A = W_out rows (cl<10, pad 0)
    f32x4 acc = {0.f, 0.f, 0.f, 0.f};
    #pragma unroll
    for (int i2 = 0; i2 < 4; ++i2) {
      const int kt = w*4 + i2;
      const int k = kt*32 + q*8;
      bf16x8 afr = {0,0,0,0,0,0,0,0};
      if (b16 < 10) {
        f32x4 v0 = *(const f32x4*)(W_out + b16*2048 + k);
        f32x4 v1 = *(const f32x4*)(W_out + b16*2048 + k + 4);
        #pragma unroll
        for (int i = 0; i < 8; ++i) afr[i] = (short)f2bf(i < 4 ? v0[i] : v1[i-4]);
      }
      const char* baddr = act
          ? (smem + A1_OFF + b16*4096 + ((((kt*4 + q) ^ b16) & 255) << 4))
          : (smem + ZP_OFF);
      bf16x8 bfr = *(const bf16x8*)baddr;
      acc = __builtin_amdgcn_mfma_f32_16x16x32_bf16(afr, bfr, acc, 0, 0, 0);
    }
    *(f32x4*)(smem + RED_OFF + ((w*64 + lane) << 4)) = acc;
  }
  __syncthreads();
  if (tid < 64) {   // reduce 16 wave-partials; lane: row = tid&15, cl = (tid>>4)*4+r
    f32x4 s = {0.f, 0.f, 0.f, 0.f};
    #pragma unroll
    for (int w2 = 0; w2 < 16; ++w2)
      s += *(const f32x4*)(smem + RED_OFF + ((w2*64 + tid) << 4));
    const int b = tid & 15, q2 = tid >> 4;
    if (b < 8) {
      #pragma unroll
      for (int r = 0; r < 4; ++r) {
        const int cl = q2*4 + r;
        if (cl < 10)
          dout[(bk*8 + b)*10 + cl] = s[r] + b_out[cl];
      }
    }
  }
}

extern "C" void kernel_launch(void* const* d_in, const int* in_sizes, int n_in,
                              void* d_out, int out_size, void* d_ws, size_t ws_size,
                              hipStream_t stream) {
  (void)in_sizes; (void)n_in; (void)ws_size; (void)out_size;
  const float* x     = (const float*)d_in[0];
  const float* W_enc = (const float*)d_in[1];
  const float* b_enc = (const float*)d_in[2];
  const float* xi    = (const float*)d_in[3];
  const float* W_out = (const float*)d_in[4];
  const float* b_out = (const float*)d_in[5];
  float* out = (float*)d_out;
  char* wsb = (char*)d_ws;   // 512 KiB fp8 tables; fully rewritten every launch

  TCons tc;
  const double OME = 2.0 * 3.14159265358979323846 * 200.0;
  const double dtd = 0.03125;
  const double co[4] = {0.0, 0.5, 0.5, 1.0};
  for (int e = 0; e < 64; ++e) {
    double t = ((double)(e >> 2) + co[e & 3]) * dtd;
    tc.s[e] = (float)sin(OME * t);
    tc.c[e] = (float)cos(OME * t);
  }

  phasenn_kernel<<<dim3(32), dim3(1024), 0, stream>>>(
      x, W_enc, b_enc, xi, W_out, b_out, out, wsb, tc);
}